// Round 2
// baseline (196.421 us; speedup 1.0000x reference)
//
#include <hip/hip_runtime.h>
#include <math.h>

// Problem constants
#define B_TOT 2048
#define S_LEN 256
#define DIN   3
#define H     128
#define DOUT  6
#define DT_C  0.1f

#define NROWS 4    // batch rows per block -> grid 512 -> 2 co-resident blocks/CU
#define HPAD  144  // bf16 row stride in sh_h: 288B -> bank stride 8, 2-way max on reads
#define PPAD  132  // f32 row stride in sh_p (head staging only)

// scale folded into W_hh/W_xh/b_hh so epilogue uses exp2 directly:
// tanh(p) = 1 - 2/(exp2(p * 2*log2e)+1)
#define PRESCALE 2.8853900817779268f   // 2*log2(e)

typedef __attribute__((ext_vector_type(8))) short short8;
typedef __attribute__((ext_vector_type(4))) float f32x4;

// row_ror:N within each 16-lane DPP row (full-rate VALU, no LDS)
template<int CTRL>
__device__ __forceinline__ float dpp_rot(float v) {
  int i = __float_as_int(v);
  int r = __builtin_amdgcn_update_dpp(i, i, CTRL, 0xF, 0xF, false);
  return __int_as_float(r);
}

// HW RNE f32->bf16 (single instruction; same rounding as the old SW pack)
__device__ __forceinline__ unsigned short cvt_bf16(float a) {
  unsigned int r;
  asm("v_cvt_pk_bf16_f32 %0, %1, %2" : "=v"(r) : "v"(a), "v"(a));
  return (unsigned short)r;
}

// LDS-only barrier: do NOT drain vmcnt (x prefetch stays in flight across steps).
// ds_write completion is covered by lgkmcnt(0); LDS is CU-local so barrier
// rendezvous after per-wave drain gives full visibility. "memory" clobber pins
// all LDS loads/stores on their side of the barrier.
__device__ __forceinline__ void lds_barrier() {
  asm volatile("s_waitcnt lgkmcnt(0)\n\ts_barrier" ::: "memory");
}

// One block = 4 batch rows, 512 threads (8 waves, 2 blocks/CU). Wave w owns
// j-tile [w*16, w*16+16); A = W_hh rows (PRESCALEd bf16, register-resident).
// B-frag read is UNMASKED with row = l16&3: lanes 4..15 of each 16-group read
// the same addresses as lanes 0..3 (LDS same-address broadcast = free), so
// every D column l16 holds valid data for batch row l16&3.
// DENSE epilogue: lane (quad,l16) ends with D[j_loc=quad*4+sel][b=l16&3],
// sel=l16>>2, gathered via 3 DPP row rotations (ror12/ror8/ror4) + 3 cndmask.
// Every lane owns exactly 1 h-element: j = w*16 + quad*4 + sel, b = l16&3.
// ONE lgkm-only barrier per step; ping-pong h buffers; 2-deep x prefetch.
__launch_bounds__(512, 4)
__global__ void ltc_kernel(const float* __restrict__ x,
                           const float* __restrict__ W_xh,
                           const float* __restrict__ W_hh,
                           const float* __restrict__ b_hh,
                           const float* __restrict__ log_tau,
                           const float* __restrict__ fc_W,
                           const float* __restrict__ fc_b,
                           float* __restrict__ out) {
  __shared__ alignas(16) unsigned short sh_h[2][NROWS][HPAD];  // ping-pong h bf16
  __shared__ alignas(16) float sh_p[NROWS][PPAD];              // final h fp32 for head

  const int tid  = threadIdx.x;
  const int w    = tid >> 6;        // wave 0..7 -> j-tile [w*16, w*16+16)
  const int lane = tid & 63;
  const int quad = lane >> 4;       // 0..3
  const int l16  = lane & 15;
  const int brow = l16 & 3;         // batch row 0..3
  const int sel  = l16 >> 2;        // which D-reg this lane owns (0..3)
  const int rb0  = blockIdx.x * NROWS;

  // ---- zero both h buffers ----
  {
    uint4* p = (uint4*)&sh_h[0][0][0];
    const int n16 = (2 * NROWS * HPAD) / 8;  // shorts -> uint4 count
    for (int i = tid; i < n16; i += 512) p[i] = make_uint4(0, 0, 0, 0);
  }

  // ---- W_hh A-fragments (PRESCALE*W, RNE bf16), register-resident ----
  // A[m=l16][k = kc*32 + quad*8 + i],  j = w*16 + m
  short8 wa[4];
  {
    const int jj = w * 16 + l16;
#pragma unroll
    for (int kc = 0; kc < 4; ++kc) {
      const float* src = W_hh + jj * H + kc * 32 + quad * 8;
#pragma unroll
      for (int i = 0; i < 8; ++i)
        wa[kc][i] = (short)cvt_bf16(src[i] * PRESCALE);
    }
  }

  // ---- per-lane epilogue params for its single element j ----
  const int j = w * 16 + quad * 4 + sel;
  const float ewx0 = W_xh[j * 3 + 0] * PRESCALE;
  const float ewx1 = W_xh[j * 3 + 1] * PRESCALE;
  const float ewx2 = W_xh[j * 3 + 2] * PRESCALE;
  const float ebh  = b_hh[j] * PRESCALE;
  float tau, ecc, ea, encc2;
  {
    float lt = log_tau[j];
    tau   = logf(1.f + expf(lt)) + 0.001f;   // softplus + eps, exact fp32, once
    ecc   = DT_C / tau;
    ea    = 1.f - ecc;
    encc2 = -2.f * ecc;
  }

  float hreg = 0.f;  // fp32 h for (brow, j), register-resident

  // static LDS offsets (shorts)
  const int rd_off = brow * HPAD + quad * 8;   // B-frag read (+ kc*32), 4-way bcast
  const int wr_off = brow * HPAD + j;          // dense 2B h' store
  unsigned short* __restrict__ buf0 = &sh_h[0][0][0];
  unsigned short* __restrict__ buf1 = &sh_h[1][0][0];

  // ---- x prefetch: 2 iterations deep (12 floats) so HBM latency (~900cy)
  //      is covered by ~2 step-pairs; barriers no longer drain vmcnt ----
  const float* xq = x + (size_t)(rb0 + brow) * (S_LEN * DIN);
  float2 pa0 = *(const float2*)(xq);
  float2 pb0 = *(const float2*)(xq + 2);
  float2 pc0 = *(const float2*)(xq + 4);
  float2 pa1 = *(const float2*)(xq + 6);
  float2 pb1 = *(const float2*)(xq + 8);
  float2 pc1 = *(const float2*)(xq + 10);
  xq += 12;

  __syncthreads();

  auto do_step = [&](unsigned short* __restrict__ cur,
                     unsigned short* __restrict__ nxt,
                     float xc0, float xc1, float xc2) {
    // B-fragments of h^T (all 64 lanes; 4-way same-address broadcast)
    short8 b0 = *(const short8*)(cur + rd_off);
    short8 b1 = *(const short8*)(cur + rd_off + 32);
    short8 b2 = *(const short8*)(cur + rd_off + 64);
    short8 b3 = *(const short8*)(cur + rd_off + 96);

    // x-projection term for this lane's element (hidden under ds_read latency)
    float t = __builtin_fmaf(xc2, ewx2, ebh);
    t = __builtin_fmaf(xc1, ewx1, t);
    t = __builtin_fmaf(xc0, ewx0, t);

    // two independent 2-deep MFMA chains (halves dependent-MFMA latency)
    f32x4 a0 = {0.f, 0.f, 0.f, 0.f};
    f32x4 a1 = {0.f, 0.f, 0.f, 0.f};
    a0 = __builtin_amdgcn_mfma_f32_16x16x32_bf16(wa[0], b0, a0, 0, 0, 0);
    a1 = __builtin_amdgcn_mfma_f32_16x16x32_bf16(wa[2], b2, a1, 0, 0, 0);
    a0 = __builtin_amdgcn_mfma_f32_16x16x32_bf16(wa[1], b1, a0, 0, 0, 0);
    a1 = __builtin_amdgcn_mfma_f32_16x16x32_bf16(wa[3], b3, a1, 0, 0, 0);

    const float d0 = a0[0] + a1[0];
    const float d1 = a0[1] + a1[1];
    const float d2 = a0[2] + a1[2];
    const float d3 = a0[3] + a1[3];

    // dense redistribution: lane needs reg 'sel' from lane (quad, l16&3).
    // B-col duplication means source data is already on lanes l16-4k.
    float r1 = dpp_rot<0x12C>(d1);   // row_ror:12 -> dst[i] = src[i-4]
    float r2 = dpp_rot<0x128>(d2);   // row_ror:8  -> dst[i] = src[i-8]
    float r3 = dpp_rot<0x124>(d3);   // row_ror:4  -> dst[i] = src[i-12]
    float pre = d0;
    pre = (sel == 1) ? r1 : pre;
    pre = (sel == 2) ? r2 : pre;
    pre = (sel == 3) ? r3 : pre;

    // epilogue: 1 element/lane
    float e  = __builtin_amdgcn_exp2f(pre + t);
    float rc = __builtin_amdgcn_rcpf(e + 1.f);
    hreg = __builtin_fmaf(encc2, rc, __builtin_fmaf(hreg, ea, ecc));

    *(unsigned short*)(nxt + wr_off) = cvt_bf16(hreg);  // dense 2B store
    lds_barrier();
  };

  for (int s = 0; s < S_LEN; s += 2) {
    float2 xa = pa0, xb = pb0, xc = pc0;
    pa0 = pa1; pb0 = pb1; pc0 = pc1;
    if (s + 4 < S_LEN) {             // uniform branch; prefetch pair s/2+2
      pa1 = *(const float2*)(xq);
      pb1 = *(const float2*)(xq + 2);
      pc1 = *(const float2*)(xq + 4);
      xq += 6;
    }
    do_step(buf0, buf1, xa.x, xa.y, xb.x);
    do_step(buf1, buf0, xb.y, xc.x, xc.y);
  }

  // ---- final head: params = softplus(h @ fc_W^T + fc_b), [4 x 6] per block ----
  sh_p[brow][j] = hreg;              // 512 distinct (brow, j) slots
  __syncthreads();

  if (tid < NROWS * DOUT) {
    const int b = tid / DOUT;
    const int o = tid - b * DOUT;
    const float* fw = fc_W + o * H;
    float acc = fc_b[o];
#pragma unroll 4
    for (int k = 0; k < H; ++k) acc += sh_p[b][k] * fw[k];
    float sp = (acc > 15.f) ? acc : logf(1.f + expf(acc));
    out[(rb0 + b) * DOUT + o] = sp;
  }
}

extern "C" void kernel_launch(void* const* d_in, const int* in_sizes, int n_in,
                              void* d_out, int out_size, void* d_ws, size_t ws_size,
                              hipStream_t stream) {
  const float* x       = (const float*)d_in[0];
  const float* W_xh    = (const float*)d_in[1];
  const float* W_hh    = (const float*)d_in[2];
  const float* b_hh    = (const float*)d_in[3];
  const float* log_tau = (const float*)d_in[4];
  const float* fc_W    = (const float*)d_in[5];
  const float* fc_b    = (const float*)d_in[6];
  float* out           = (float*)d_out;

  ltc_kernel<<<dim3(B_TOT / NROWS), dim3(512), 0, stream>>>(
      x, W_xh, W_hh, b_hh, log_tau, fc_W, fc_b, out);
}

// Round 3
// 186.179 us; speedup vs baseline: 1.0550x; 1.0550x over previous
//
#include <hip/hip_runtime.h>
#include <math.h>

// Problem constants
#define B_TOT 2048
#define S_LEN 256
#define DIN   3
#define H     128
#define DOUT  6
#define DT_C  0.1f

#define NROWS 8    // batch rows per block (valid cols of the n=16 MFMA face)
#define PPAD  132  // f32 row stride in sh_p (head staging only)

// scale folded into W_hh/W_xh/b_hh so epilogue uses exp2 directly:
// tanh(p) = 1 - 2/(exp2(p * 2*log2e)+1)
#define PRESCALE 2.8853900817779268f   // 2*log2(e)

typedef __attribute__((ext_vector_type(8))) short short8;
typedef __attribute__((ext_vector_type(4))) float f32x4;

// lane-pair exchange lane <-> lane^8 within 16-lane DPP row (full-rate VALU)
__device__ __forceinline__ float dpp_xor8(float v) {
  int i = __float_as_int(v);
  int r = __builtin_amdgcn_update_dpp(i, i, 0x128 /*row_ror:8*/, 0xF, 0xF, false);
  return __int_as_float(r);
}

// HW RNE f32x2 -> packed bf16x2 (single instruction; validated in R2: absmax
// identical to the SW RNE pack)
__device__ __forceinline__ unsigned int cvt_pk_bf16(float a, float b) {
  unsigned int r;
  asm("v_cvt_pk_bf16_f32 %0, %1, %2" : "=v"(r) : "v"(a), "v"(b));
  return r;
}

// LDS-only barrier: do NOT drain vmcnt (x prefetch stays in flight across
// steps). lgkmcnt(0) covers this wave's ds_read/ds_write completion before
// rendezvous. "memory" clobber pins LDS ops on their side. Validated in R2.
__device__ __forceinline__ void lds_barrier() {
  asm volatile("s_waitcnt lgkmcnt(0)\n\ts_barrier" ::: "memory");
}

// One block = 8 batch rows, 512 threads (8 waves, 2/SIMD), grid 256 = 1/CU.
// Wave w owns j-tile [w*16, w*16+16); A = W_hh rows (PRESCALEd bf16,
// register-resident). MFMA D[m=j_loc][n=b], lane holds (b=l16, j_loc=quad*4+r).
//
// h exchange LDS layout is PRE-SWIZZLED into B-fragment order ("hswz"):
//   16B slot index (kc,quad,b) = kc*32 + quad*8 + b   holds h[b][kc*32+quad*8 .. +8]
// Reader lane (quad,l16<8): slot = kc*32 + quad*8 + l16 -> the 32 active lanes
// read 32 CONSECUTIVE 16B slots per ds_read_b128: perfect 32-bank tiling,
// zero conflicts, 4-cycle minimum (vs ~16 extra cyc/read in the row-major
// layout, 4.19M conflict cycles/dispatch measured in R0).
// Writer lane owns (b=l16&7, j0 = w*16+quad*4+(l16>>3)*2): one dword at
//   shorts-offset (j0>>5)*256 + ((j0>>3)&3)*64 + b*8 + (j0&7)  (<=2-way, free).
//
// DENSE epilogue via DPP row_ror:8 (proven in R0 kernel): lane b keeps regs
// r=0,1; partner lane b+8 receives r=2,3. Every lane owns 2 elems all 256 steps.
// ONE lgkm-only barrier per step; ping-pong h buffers; 2-deep x prefetch.
__launch_bounds__(512, 2)
__global__ void ltc_kernel(const float* __restrict__ x,
                           const float* __restrict__ W_xh,
                           const float* __restrict__ W_hh,
                           const float* __restrict__ b_hh,
                           const float* __restrict__ log_tau,
                           const float* __restrict__ fc_W,
                           const float* __restrict__ fc_b,
                           float* __restrict__ out) {
  __shared__ alignas(16) unsigned short sh_h[2][1024];   // ping-pong, 2KB each
  __shared__ alignas(16) float sh_p[NROWS][PPAD];        // final h fp32 for head

  const int tid  = threadIdx.x;
  const int w    = tid >> 6;        // wave 0..7 -> j-tile [w*16, w*16+16)
  const int lane = tid & 63;
  const int quad = lane >> 4;       // 0..3
  const int l16  = lane & 15;       // b-column in B/D fragments
  const int rb0  = blockIdx.x * NROWS;

  // ---- zero both h buffers ----
  {
    uint4* p = (uint4*)&sh_h[0][0];
    const int n16 = (2 * 1024) / 8;  // shorts -> uint4 count
    for (int i = tid; i < n16; i += 512) p[i] = make_uint4(0, 0, 0, 0);
  }

  // ---- W_hh A-fragments (PRESCALE*W, RNE bf16), register-resident ----
  // A[m=l16][k = kc*32 + quad*8 + i],  j = w*16 + m
  short8 wa[4];
  {
    const int jj = w * 16 + l16;
#pragma unroll
    for (int kc = 0; kc < 4; ++kc) {
      const float* src = W_hh + jj * H + kc * 32 + quad * 8;
#pragma unroll
      for (int i = 0; i < 8; ++i) {
        unsigned int pk = cvt_pk_bf16(src[i] * PRESCALE, 0.f);
        wa[kc][i] = (short)(pk & 0xFFFFu);
      }
    }
  }

  // ---- dense epilogue mapping: lane owns (b=l16&7, j0=w*16+quad*4+(l16>>3)*2+{0,1}) ----
  const int brow = l16 & 7;
  const int rbse = (l16 >> 3) * 2;            // 0 for lanes b, 2 for partners b+8
  const int j0   = w * 16 + quad * 4 + rbse;
  float ewx[2][3], ebh[2], ecc[2], ea[2], encc2[2];
#pragma unroll
  for (int r = 0; r < 2; ++r) {
    const int j = j0 + r;
    ewx[r][0] = W_xh[j * 3 + 0] * PRESCALE;
    ewx[r][1] = W_xh[j * 3 + 1] * PRESCALE;
    ewx[r][2] = W_xh[j * 3 + 2] * PRESCALE;
    ebh[r]    = b_hh[j] * PRESCALE;
    float lt  = log_tau[j];
    float tau = logf(1.f + expf(lt)) + 0.001f;   // softplus + eps, exact fp32
    float cc  = DT_C / tau;
    ecc[r]    = cc;
    ea[r]     = 1.f - cc;
    encc2[r]  = -2.f * cc;
  }
  const bool lowhalf = (l16 < 8);
  const float* xp = x + (size_t)(rb0 + brow) * (S_LEN * DIN);

  float hreg[2] = {0.f, 0.f};  // fp32 h for (brow, j0..j0+1), register-resident

  // static LDS offsets (shorts)
  const int rd_off = quad * 64 + l16 * 8;                        // + kc*256; l16<8
  const int wr_off = (j0 >> 5) * 256 + ((j0 >> 3) & 3) * 64 + brow * 8 + (j0 & 7);
  unsigned short* __restrict__ buf0 = &sh_h[0][0];
  unsigned short* __restrict__ buf1 = &sh_h[1][0];

  // persistent B-frag regs: zeroed ONCE; lanes l16>=8 never overwrite them
  short8 bf[4];
#pragma unroll
  for (int kc = 0; kc < 4; ++kc) bf[kc] = short8{0, 0, 0, 0, 0, 0, 0, 0};

  // ---- x prefetch: 2 step-pairs deep (12 floats); barriers don't drain vmcnt,
  //      so these stay in flight across steps ----
  const float* xq = xp;
  float2 pa0 = *(const float2*)(xq);
  float2 pb0 = *(const float2*)(xq + 2);
  float2 pc0 = *(const float2*)(xq + 4);
  float2 pa1 = *(const float2*)(xq + 6);
  float2 pb1 = *(const float2*)(xq + 8);
  float2 pc1 = *(const float2*)(xq + 10);
  xq += 12;

  __syncthreads();

  auto do_step = [&](const unsigned short* __restrict__ cur,
                     unsigned short* __restrict__ nxt,
                     float xc0, float xc1, float xc2) {
    // B-fragments of h^T (masked; lanes l16>=8 keep zeros).
    // 32 active lanes read 32 consecutive 16B slots per kc: conflict-free.
    if (l16 < NROWS) {
#pragma unroll
      for (int kc = 0; kc < 4; ++kc)
        bf[kc] = *(const short8*)(cur + rd_off + kc * 256);
    }

    // x-projection terms for this lane's 2 elems (hidden under ds_read latency)
    float t0 = __builtin_fmaf(xc2, ewx[0][2], ebh[0]);
    t0 = __builtin_fmaf(xc1, ewx[0][1], t0);
    t0 = __builtin_fmaf(xc0, ewx[0][0], t0);
    float t1 = __builtin_fmaf(xc2, ewx[1][2], ebh[1]);
    t1 = __builtin_fmaf(xc1, ewx[1][1], t1);
    t1 = __builtin_fmaf(xc0, ewx[1][0], t1);

    // two independent 2-deep MFMA chains (validated in R2), then elementwise add
    f32x4 a0 = {0.f, 0.f, 0.f, 0.f};
    f32x4 a1 = {0.f, 0.f, 0.f, 0.f};
    a0 = __builtin_amdgcn_mfma_f32_16x16x32_bf16(wa[0], bf[0], a0, 0, 0, 0);
    a1 = __builtin_amdgcn_mfma_f32_16x16x32_bf16(wa[2], bf[2], a1, 0, 0, 0);
    a0 = __builtin_amdgcn_mfma_f32_16x16x32_bf16(wa[1], bf[1], a0, 0, 0, 0);
    a1 = __builtin_amdgcn_mfma_f32_16x16x32_bf16(wa[3], bf[3], a1, 0, 0, 0);

    const float d0 = a0[0] + a1[0];
    const float d1 = a0[1] + a1[1];
    const float d2 = a0[2] + a1[2];
    const float d3 = a0[3] + a1[3];

    // DPP pair-exchange: partner lanes (l16>=8) receive r=2,3 from lane l16-8
    float e2 = dpp_xor8(d2);
    float e3 = dpp_xor8(d3);
    float pre0 = lowhalf ? d0 : e2;
    float pre1 = lowhalf ? d1 : e3;

    // dense epilogue: 2 elems/lane, every lane
    {
      float e  = __builtin_amdgcn_exp2f(pre0 + t0);
      float rc = __builtin_amdgcn_rcpf(e + 1.f);
      hreg[0] = __builtin_fmaf(encc2[0], rc, __builtin_fmaf(hreg[0], ea[0], ecc[0]));
    }
    {
      float e  = __builtin_amdgcn_exp2f(pre1 + t1);
      float rc = __builtin_amdgcn_rcpf(e + 1.f);
      hreg[1] = __builtin_fmaf(encc2[1], rc, __builtin_fmaf(hreg[1], ea[1], ecc[1]));
    }

    // dense 4B store into the pre-swizzled layout (<=2-way bank, free)
    *(unsigned int*)(nxt + wr_off) = cvt_pk_bf16(hreg[0], hreg[1]);
    lds_barrier();
  };

  for (int s = 0; s < S_LEN; s += 2) {
    float2 xa = pa0, xb = pb0, xc = pc0;
    pa0 = pa1; pb0 = pb1; pc0 = pc1;
    if (s + 4 < S_LEN) {             // uniform branch; prefetch pair s/2+2
      pa1 = *(const float2*)(xq);
      pb1 = *(const float2*)(xq + 2);
      pc1 = *(const float2*)(xq + 4);
      xq += 6;
    }
    do_step(buf0, buf1, xa.x, xa.y, xb.x);
    do_step(buf1, buf0, xb.y, xc.x, xc.y);
  }

  // ---- final head: params = softplus(h @ fc_W^T + fc_b), [8 x 6] per block ----
  {
    float2 v = make_float2(hreg[0], hreg[1]);
    *(float2*)&sh_p[brow][j0] = v;   // 8B-aligned (j0 even), all lanes distinct
  }
  __syncthreads();

  if (tid < NROWS * DOUT) {
    const int b = tid / DOUT;
    const int o = tid - b * DOUT;
    const float* fw = fc_W + o * H;
    float acc = fc_b[o];
#pragma unroll 4
    for (int k = 0; k < H; ++k) acc += sh_p[b][k] * fw[k];
    float sp = (acc > 15.f) ? acc : logf(1.f + expf(acc));
    out[(rb0 + b) * DOUT + o] = sp;
  }
}

extern "C" void kernel_launch(void* const* d_in, const int* in_sizes, int n_in,
                              void* d_out, int out_size, void* d_ws, size_t ws_size,
                              hipStream_t stream) {
  const float* x       = (const float*)d_in[0];
  const float* W_xh    = (const float*)d_in[1];
  const float* W_hh    = (const float*)d_in[2];
  const float* b_hh    = (const float*)d_in[3];
  const float* log_tau = (const float*)d_in[4];
  const float* fc_W    = (const float*)d_in[5];
  const float* fc_b    = (const float*)d_in[6];
  float* out           = (float*)d_out;

  ltc_kernel<<<dim3(B_TOT / NROWS), dim3(512), 0, stream>>>(
      x, W_xh, W_hh, b_hh, log_tau, fc_W, fc_b, out);
}

// Round 11
// 160.797 us; speedup vs baseline: 1.2215x; 1.1578x over previous
//
#include <hip/hip_runtime.h>
#include <math.h>

// Problem constants
#define B_TOT 2048
#define S_LEN 256
#define DIN   3
#define H     128
#define DOUT  6
#define DT_C  0.1f

#define NROWS 16   // batch rows per block = FULL n=16 MFMA face (R0 used 8: half wasted)
#define PPAD  132  // f32 row stride in sh_p (head staging only)

// scale folded into W_hh/W_xh/b_hh so epilogue uses exp2 directly:
// tanh(p) = 1 - 2/(exp2(p * 2*log2e)+1)
#define PRESCALE 2.8853900817779268f   // 2*log2(e)

typedef __attribute__((ext_vector_type(8))) short short8;
typedef __attribute__((ext_vector_type(4))) float f32x4;

// HW RNE f32x2 -> packed bf16x2 (numerics validated in R2/R3: absmax identical
// to SW RNE pack). Low short = first operand.
__device__ __forceinline__ unsigned int cvt_pk_bf16(float a, float b) {
  unsigned int r;
  asm("v_cvt_pk_bf16_f32 %0, %1, %2" : "=v"(r) : "v"(a), "v"(b));
  return r;
}

// Structure (R4 "full-face / 4-wave"):
//   block = 256 threads (4 waves), owns NROWS=16 batch rows; grid = 128.
//   Wave w owns j-tile [w*32, w*32+32) = 2 m-tiles; 8 MFMAs/step as 4
//   independent 2-deep chains + adds. ALL 16 B-columns are valid batch rows:
//   no exec masks, no DPP exchange — dense epilogue, 8 elems/lane.
//   4-wave barrier (vs R0's 8): rendezvous/skew was the dominant per-step term.
//
// h-exchange LDS layout is PRE-SWIZZLED into B-fragment order:
//   16B slot (kc,quad,b) = kc*64 + quad*16 + b holds h[b][kc*32+quad*8 .. +8].
//   Read: lane (quad,l16) reads slot (kc,quad,l16): 64 lanes read 64
//   consecutive 16B slots per kc -> conflict-free ds_read_b128.
//   Write: lane (w,quad,l16), m-tile mt, owns j = w*32+mt*16+quad*4+r (r=0..3):
//   these 4 land in consecutive shorts i'=(quad&1)*4+r of slot
//   (kc=w, quad'=mt*2+(quad>>1), b=l16)  [check: kc*32+quad'*8+i' =
//   w*32+mt*16+(quad>>1)*8+(quad&1)*4+r = w*32+mt*16+quad*4+r = j ✓]
//   -> one 8B ds_write per m-tile (2 cvt_pk), <=4-way bank (write-side, cheap).
//
// __syncthreads() per step (R3 lesson: inline-asm barrier defeats compiler
// scheduling, +380cy/step; vmcnt drain measured negligible). ONE barrier/step;
// ping-pong buffers; 1-deep x prefetch (R0-proven pattern).
__launch_bounds__(256, 1)
__global__ void ltc_kernel(const float* __restrict__ x,
                           const float* __restrict__ W_xh,
                           const float* __restrict__ W_hh,
                           const float* __restrict__ b_hh,
                           const float* __restrict__ log_tau,
                           const float* __restrict__ fc_W,
                           const float* __restrict__ fc_b,
                           float* __restrict__ out) {
  __shared__ alignas(16) unsigned short sh_h[2][2048];   // ping-pong, 4KB each
  __shared__ alignas(16) float sh_p[NROWS][PPAD];        // final h fp32 for head

  const int tid  = threadIdx.x;
  const int w    = tid >> 6;        // wave 0..3 -> j-tile [w*32, w*32+32)
  const int lane = tid & 63;
  const int quad = lane >> 4;       // 0..3
  const int l16  = lane & 15;       // b-column in B/D fragments (batch row)
  const int rb0  = blockIdx.x * NROWS;

  // ---- zero both h buffers (h0 = 0) ----
  {
    uint4* p = (uint4*)&sh_h[0][0];
    for (int i = tid; i < 512; i += 256) p[i] = make_uint4(0, 0, 0, 0);
  }

  // ---- W_hh A-fragments (PRESCALE*W, RNE bf16), register-resident ----
  // A[m=l16][k = kc*32 + quad*8 + i] for m-tile mt: j-row = w*32 + mt*16 + l16
  short8 wa[2][4];
#pragma unroll
  for (int mt = 0; mt < 2; ++mt) {
#pragma unroll
    for (int kc = 0; kc < 4; ++kc) {
      const float* src = W_hh + (w * 32 + mt * 16 + l16) * H + kc * 32 + quad * 8;
#pragma unroll
      for (int i = 0; i < 8; ++i)
        wa[mt][kc][i] = (short)(cvt_pk_bf16(src[i] * PRESCALE, 0.f) & 0xFFFFu);
    }
  }

  // ---- per-lane epilogue params: 8 elems, j = w*32 + mt*16 + quad*4 + r ----
  float ewx[2][4][3], ebh[2][4], ecc[2][4], ea[2][4], encc2[2][4];
#pragma unroll
  for (int mt = 0; mt < 2; ++mt) {
#pragma unroll
    for (int r = 0; r < 4; ++r) {
      const int j = w * 32 + mt * 16 + quad * 4 + r;
      ewx[mt][r][0] = W_xh[j * 3 + 0] * PRESCALE;
      ewx[mt][r][1] = W_xh[j * 3 + 1] * PRESCALE;
      ewx[mt][r][2] = W_xh[j * 3 + 2] * PRESCALE;
      ebh[mt][r]    = b_hh[j] * PRESCALE;
      float lt  = log_tau[j];
      float tau = logf(1.f + expf(lt)) + 0.001f;   // softplus + eps, fp32, once
      float cc  = DT_C / tau;
      ecc[mt][r]   = cc;
      ea[mt][r]    = 1.f - cc;
      encc2[mt][r] = -2.f * cc;
    }
  }

  float hreg[2][4];   // fp32 h for (b=l16, lane's 8 j), register-resident
#pragma unroll
  for (int mt = 0; mt < 2; ++mt)
#pragma unroll
    for (int r = 0; r < 4; ++r) hreg[mt][r] = 0.f;

  // static LDS offsets (shorts)
  const int rd_off  = quad * 128 + l16 * 8;   // + kc*512; full exec, conflict-free
  const int wr_off0 = (w * 64 + (0 * 2 + (quad >> 1)) * 16 + l16) * 8 + (quad & 1) * 4;
  const int wr_off1 = (w * 64 + (1 * 2 + (quad >> 1)) * 16 + l16) * 8 + (quad & 1) * 4;
  unsigned short* __restrict__ buf0 = &sh_h[0][0];
  unsigned short* __restrict__ buf1 = &sh_h[1][0];

  // ---- x prefetch (R0-proven 1-deep pattern): 6 floats per 2-step pair ----
  const float* xp = x + (size_t)(rb0 + l16) * (S_LEN * DIN);
  float2 pfa = *(const float2*)(xp);
  float2 pfb = *(const float2*)(xp + 2);
  float2 pfc = *(const float2*)(xp + 4);

  __syncthreads();

  auto do_step = [&](const unsigned short* __restrict__ cur,
                     unsigned short* __restrict__ nxt,
                     float xc0, float xc1, float xc2) {
    // B-fragments of h^T: 64 lanes read 64 consecutive 16B slots per kc
    short8 b0 = *(const short8*)(cur + rd_off);
    short8 b1 = *(const short8*)(cur + rd_off + 512);
    short8 b2 = *(const short8*)(cur + rd_off + 1024);
    short8 b3 = *(const short8*)(cur + rd_off + 1536);

    // x-projection for the lane's 8 elems (issues under ds_read latency)
    float t[2][4];
#pragma unroll
    for (int mt = 0; mt < 2; ++mt)
#pragma unroll
      for (int r = 0; r < 4; ++r) {
        float v = __builtin_fmaf(xc2, ewx[mt][r][2], ebh[mt][r]);
        v = __builtin_fmaf(xc1, ewx[mt][r][1], v);
        t[mt][r] = __builtin_fmaf(xc0, ewx[mt][r][0], v);
      }

    // 8 MFMAs: 4 independent 2-deep chains (2 per m-tile), then adds
    f32x4 aA0 = {0.f, 0.f, 0.f, 0.f}, aB0 = {0.f, 0.f, 0.f, 0.f};
    f32x4 aA1 = {0.f, 0.f, 0.f, 0.f}, aB1 = {0.f, 0.f, 0.f, 0.f};
    aA0 = __builtin_amdgcn_mfma_f32_16x16x32_bf16(wa[0][0], b0, aA0, 0, 0, 0);
    aA1 = __builtin_amdgcn_mfma_f32_16x16x32_bf16(wa[1][0], b0, aA1, 0, 0, 0);
    aB0 = __builtin_amdgcn_mfma_f32_16x16x32_bf16(wa[0][2], b2, aB0, 0, 0, 0);
    aB1 = __builtin_amdgcn_mfma_f32_16x16x32_bf16(wa[1][2], b2, aB1, 0, 0, 0);
    aA0 = __builtin_amdgcn_mfma_f32_16x16x32_bf16(wa[0][1], b1, aA0, 0, 0, 0);
    aA1 = __builtin_amdgcn_mfma_f32_16x16x32_bf16(wa[1][1], b1, aA1, 0, 0, 0);
    aB0 = __builtin_amdgcn_mfma_f32_16x16x32_bf16(wa[0][3], b3, aB0, 0, 0, 0);
    aB1 = __builtin_amdgcn_mfma_f32_16x16x32_bf16(wa[1][3], b3, aB1, 0, 0, 0);

    // dense epilogue: 8 elems/lane, every lane, no masks, no DPP
#pragma unroll
    for (int r = 0; r < 4; ++r) {
      {
        float pre = aA0[r] + aB0[r];
        float e   = __builtin_amdgcn_exp2f(pre + t[0][r]);
        float rc  = __builtin_amdgcn_rcpf(e + 1.f);
        hreg[0][r] = __builtin_fmaf(encc2[0][r], rc,
                     __builtin_fmaf(hreg[0][r], ea[0][r], ecc[0][r]));
      }
      {
        float pre = aA1[r] + aB1[r];
        float e   = __builtin_amdgcn_exp2f(pre + t[1][r]);
        float rc  = __builtin_amdgcn_rcpf(e + 1.f);
        hreg[1][r] = __builtin_fmaf(encc2[1][r], rc,
                     __builtin_fmaf(hreg[1][r], ea[1][r], ecc[1][r]));
      }
    }

    // 2x 8B stores into the pre-swizzled layout (4 consecutive shorts each)
    {
      uint2 v0, v1;
      v0.x = cvt_pk_bf16(hreg[0][0], hreg[0][1]);
      v0.y = cvt_pk_bf16(hreg[0][2], hreg[0][3]);
      v1.x = cvt_pk_bf16(hreg[1][0], hreg[1][1]);
      v1.y = cvt_pk_bf16(hreg[1][2], hreg[1][3]);
      *(uint2*)(nxt + wr_off0) = v0;
      *(uint2*)(nxt + wr_off1) = v1;
    }
    __syncthreads();
  };

  for (int s = 0; s < S_LEN; s += 2) {
    float2 xa = pfa, xb = pfb, xc = pfc;
    if (s + 2 < S_LEN) {             // uniform branch; prefetch next pair
      xp += 6;
      pfa = *(const float2*)(xp);
      pfb = *(const float2*)(xp + 2);
      pfc = *(const float2*)(xp + 4);
    }
    do_step(buf0, buf1, xa.x, xa.y, xb.x);
    do_step(buf1, buf0, xb.y, xc.x, xc.y);
  }

  // ---- final head: params = softplus(h @ fc_W^T + fc_b), [16 x 6]/block ----
  {
    float4 v0 = make_float4(hreg[0][0], hreg[0][1], hreg[0][2], hreg[0][3]);
    float4 v1 = make_float4(hreg[1][0], hreg[1][1], hreg[1][2], hreg[1][3]);
    *(float4*)&sh_p[l16][w * 32 + quad * 4]      = v0;  // 16B-aligned
    *(float4*)&sh_p[l16][w * 32 + 16 + quad * 4] = v1;
  }
  __syncthreads();

  if (tid < NROWS * DOUT) {
    const int b = tid / DOUT;
    const int o = tid - b * DOUT;
    const float* fw = fc_W + o * H;
    float acc = fc_b[o];
#pragma unroll 4
    for (int k = 0; k < H; ++k) acc += sh_p[b][k] * fw[k];
    float sp = (acc > 15.f) ? acc : logf(1.f + expf(acc));
    out[(rb0 + b) * DOUT + o] = sp;
  }
}

extern "C" void kernel_launch(void* const* d_in, const int* in_sizes, int n_in,
                              void* d_out, int out_size, void* d_ws, size_t ws_size,
                              hipStream_t stream) {
  const float* x       = (const float*)d_in[0];
  const float* W_xh    = (const float*)d_in[1];
  const float* W_hh    = (const float*)d_in[2];
  const float* b_hh    = (const float*)d_in[3];
  const float* log_tau = (const float*)d_in[4];
  const float* fc_W    = (const float*)d_in[5];
  const float* fc_b    = (const float*)d_in[6];
  float* out           = (float*)d_out;

  ltc_kernel<<<dim3(B_TOT / NROWS), dim3(256), 0, stream>>>(
      x, W_xh, W_hh, b_hh, log_tau, fc_W, fc_b, out);
}

// Round 13
// 137.772 us; speedup vs baseline: 1.4257x; 1.1671x over previous
//
#include <hip/hip_runtime.h>
#include <math.h>

// Problem constants
#define B_TOT 2048
#define S_LEN 256
#define DIN   3
#define H     128
#define DOUT  6
#define DT_C  0.1f

#define NROWS 8    // batch rows per block (R0 structure: proven 870cy/step best)
#define HPAD  136  // bf16 row stride in sh_h (128 + 8 pad), rows 16B-aligned
#define PPAD  132  // f32 row stride in sh_p (head staging only)
#define XPAD  772  // f32 row stride in sh_x (768 + 4): rows on distinct banks

// scale folded into W_hh/W_xh/b_hh so epilogue uses exp2 directly:
// tanh(p) = 1 - 2/(exp2(p * 2*log2e)+1)
#define PRESCALE 2.8853900817779268f   // 2*log2(e)

typedef __attribute__((ext_vector_type(8))) short short8;
typedef __attribute__((ext_vector_type(4))) float f32x4;

// lane-pair exchange lane <-> lane^8 within 16-lane DPP row (full-rate VALU)
__device__ __forceinline__ float dpp_xor8(float v) {
  int i = __float_as_int(v);
  int r = __builtin_amdgcn_update_dpp(i, i, 0x128 /*row_ror:8*/, 0xF, 0xF, false);
  return __int_as_float(r);
}

// HW RNE f32x2 -> packed bf16x2 (validated R2/R3: absmax identical to SW pack)
__device__ __forceinline__ unsigned int cvt_pk_bf16(float a, float b) {
  unsigned int r;
  asm("v_cvt_pk_bf16_f32 %0, %1, %2" : "=v"(r) : "v"(a), "v"(b));
  return r;
}

// R5 = R0 structure (8 rows, 8 waves, 512thr, grid 256 = 1 block/CU, proven
// 870cy/step) with two chain-term fixes:
//  (1) x staged ENTIRELY in LDS at prologue: the main loop issues ZERO global
//      memory ops, so __syncthreads()'s vmcnt(0) drain is free (R0 drained the
//      in-flight x prefetch every step; R3's asm lgkm-only barrier fixed that
//      but broke compiler scheduling, +380cy/step). Keep plain __syncthreads.
//  (2) 4-deep dependent MFMA chain -> 2x2 independent chains + f32 adds
//      (numerics validated R2/R3): removes ~2 dependent-MFMA latencies.
// All else identical to R0: masked B-frag reads (l16<8, persistent zeros),
// DPP row_ror:8 dense epilogue (2 elems/lane), ping-pong h buffers, one
// barrier/step, dword-packed h' store.
__launch_bounds__(512, 2)
__global__ void ltc_kernel(const float* __restrict__ x,
                           const float* __restrict__ W_xh,
                           const float* __restrict__ W_hh,
                           const float* __restrict__ b_hh,
                           const float* __restrict__ log_tau,
                           const float* __restrict__ fc_W,
                           const float* __restrict__ fc_b,
                           float* __restrict__ out) {
  __shared__ alignas(16) unsigned short sh_h[2][NROWS][HPAD];  // ping-pong h bf16
  __shared__ alignas(16) float sh_x[NROWS][XPAD];              // whole x tile (24KB)
  __shared__ alignas(16) float sh_p[NROWS][PPAD];              // final h fp32 for head

  const int tid  = threadIdx.x;
  const int w    = tid >> 6;        // wave 0..7 -> j-tile [w*16, w*16+16)
  const int lane = tid & 63;
  const int quad = lane >> 4;       // 0..3
  const int l16  = lane & 15;       // b-column in B/D fragments
  const int rb0  = blockIdx.x * NROWS;

  // ---- zero both h buffers ----
  {
    uint4* p = (uint4*)&sh_h[0][0][0];
    const int n16 = (2 * NROWS * HPAD) / 8;  // shorts -> uint4 count
    for (int i = tid; i < n16; i += 512) p[i] = make_uint4(0, 0, 0, 0);
  }

  // ---- stage x for the block's 8 rows into LDS (768 f32/row, pad to 772) ----
  // 8*192 float4 chunks, coalesced 16B loads; prologue-only (off the loop)
  {
    const float* srcx = x + (size_t)rb0 * (S_LEN * DIN);
    for (int i = tid; i < NROWS * 192; i += 512) {
      const int r  = i / 192;
      const int c4 = i - r * 192;
      *(float4*)&sh_x[r][c4 * 4] =
          *(const float4*)(srcx + (size_t)r * (S_LEN * DIN) + c4 * 4);
    }
  }

  // ---- W_hh A-fragments (PRESCALE*W, RNE bf16), register-resident ----
  // A[m=l16][k = kc*32 + quad*8 + i],  j = w*16 + m
  short8 wa[4];
  {
    const int jj = w * 16 + l16;
#pragma unroll
    for (int kc = 0; kc < 4; ++kc) {
      const float* src = W_hh + jj * H + kc * 32 + quad * 8;
#pragma unroll
      for (int i = 0; i < 8; ++i)
        wa[kc][i] = (short)(cvt_pk_bf16(src[i] * PRESCALE, 0.f) & 0xFFFFu);
    }
  }

  // ---- dense epilogue mapping: lane owns (b=l16&7, j0=w*16+quad*4+(l16>>3)*2+{0,1}) ----
  const int brow = l16 & 7;
  const int rbse = (l16 >> 3) * 2;            // 0 for lanes b, 2 for partners b+8
  const int j0   = w * 16 + quad * 4 + rbse;
  float ewx[2][3], ebh[2], ecc[2], ea[2], encc2[2];
#pragma unroll
  for (int r = 0; r < 2; ++r) {
    const int j = j0 + r;
    ewx[r][0] = W_xh[j * 3 + 0] * PRESCALE;
    ewx[r][1] = W_xh[j * 3 + 1] * PRESCALE;
    ewx[r][2] = W_xh[j * 3 + 2] * PRESCALE;
    ebh[r]    = b_hh[j] * PRESCALE;
    float lt  = log_tau[j];
    float tau = logf(1.f + expf(lt)) + 0.001f;   // softplus + eps, exact fp32
    float cc  = DT_C / tau;
    ecc[r]    = cc;
    ea[r]     = 1.f - cc;
    encc2[r]  = -2.f * cc;
  }
  const bool lowhalf = (l16 < 8);

  float hreg[2] = {0.f, 0.f};  // fp32 h for (brow, j0..j0+1), register-resident

  // static LDS offsets (shorts)
  const int rd_off = l16 * HPAD + quad * 8;    // B-frag read (+ kc*32), l16<8
  const int wr_off = brow * HPAD + j0;         // dense 4B h' store
  const unsigned short* __restrict__ buf0 = &sh_h[0][0][0];
  unsigned short* __restrict__ buf1 = &sh_h[1][0][0];

  // persistent B-frag regs: zeroed ONCE; lanes l16>=8 never overwrite them
  short8 bf[4];
#pragma unroll
  for (int kc = 0; kc < 4; ++kc) bf[kc] = short8{0, 0, 0, 0, 0, 0, 0, 0};

  __syncthreads();   // sh_h zeroed + sh_x staged visible to all waves

  // ---- x prefetch from LDS: 6 floats per 2-step pair, 1 pair ahead.
  //      ds_read latency (~120cy) << pair length; NO vmem in the loop ----
  const float* xrow = &sh_x[brow][0];
  float2 pfa = *(const float2*)(xrow);
  float2 pfb = *(const float2*)(xrow + 2);
  float2 pfc = *(const float2*)(xrow + 4);
  const float* xq = xrow + 6;

  auto do_step = [&](const unsigned short* __restrict__ cur,
                     unsigned short* __restrict__ nxt,
                     float xc0, float xc1, float xc2) {
    // B-fragments of h^T (masked; lanes l16>=8 keep zeros)
    if (l16 < NROWS) {
#pragma unroll
      for (int kc = 0; kc < 4; ++kc)
        bf[kc] = *(const short8*)(cur + rd_off + kc * 32);
    }

    // x-projection terms for this lane's 2 elems (issue under ds_read shadow)
    float t0 = __builtin_fmaf(xc2, ewx[0][2], ebh[0]);
    t0 = __builtin_fmaf(xc1, ewx[0][1], t0);
    t0 = __builtin_fmaf(xc0, ewx[0][0], t0);
    float t1 = __builtin_fmaf(xc2, ewx[1][2], ebh[1]);
    t1 = __builtin_fmaf(xc1, ewx[1][1], t1);
    t1 = __builtin_fmaf(xc0, ewx[1][0], t1);

    // two independent 2-deep MFMA chains + elementwise add (R2/R3-validated)
    f32x4 a0 = {0.f, 0.f, 0.f, 0.f};
    f32x4 a1 = {0.f, 0.f, 0.f, 0.f};
    a0 = __builtin_amdgcn_mfma_f32_16x16x32_bf16(wa[0], bf[0], a0, 0, 0, 0);
    a1 = __builtin_amdgcn_mfma_f32_16x16x32_bf16(wa[2], bf[2], a1, 0, 0, 0);
    a0 = __builtin_amdgcn_mfma_f32_16x16x32_bf16(wa[1], bf[1], a0, 0, 0, 0);
    a1 = __builtin_amdgcn_mfma_f32_16x16x32_bf16(wa[3], bf[3], a1, 0, 0, 0);

    const float d0 = a0[0] + a1[0];
    const float d1 = a0[1] + a1[1];
    const float d2 = a0[2] + a1[2];
    const float d3 = a0[3] + a1[3];

    // DPP pair-exchange: partner lanes (l16>=8) receive r=2,3 from lane l16-8
    float e2 = dpp_xor8(d2);
    float e3 = dpp_xor8(d3);
    float pre0 = lowhalf ? d0 : e2;
    float pre1 = lowhalf ? d1 : e3;

    // dense epilogue: 2 elems/lane, every lane
    {
      float e  = __builtin_amdgcn_exp2f(pre0 + t0);
      float rc = __builtin_amdgcn_rcpf(e + 1.f);
      hreg[0] = __builtin_fmaf(encc2[0], rc, __builtin_fmaf(hreg[0], ea[0], ecc[0]));
    }
    {
      float e  = __builtin_amdgcn_exp2f(pre1 + t1);
      float rc = __builtin_amdgcn_rcpf(e + 1.f);
      hreg[1] = __builtin_fmaf(encc2[1], rc, __builtin_fmaf(hreg[1], ea[1], ecc[1]));
    }

    *(unsigned int*)(nxt + wr_off) = cvt_pk_bf16(hreg[0], hreg[1]);  // 4B store
    __syncthreads();   // vmcnt(0) part is free: no vmem ops in the loop
  };

  for (int s = 0; s < S_LEN; s += 2) {
    float2 xa = pfa, xb = pfb, xc = pfc;
    if (s + 2 < S_LEN) {             // uniform branch; prefetch next pair (LDS)
      pfa = *(const float2*)(xq);
      pfb = *(const float2*)(xq + 2);
      pfc = *(const float2*)(xq + 4);
      xq += 6;
    }
    do_step(buf0, buf1, xa.x, xa.y, xb.x);
    do_step(buf1, (unsigned short*)buf0, xb.y, xc.x, xc.y);
  }

  // ---- final head: params = softplus(h @ fc_W^T + fc_b), [8 x 6] per block ----
  {
    float2 v = make_float2(hreg[0], hreg[1]);
    *(float2*)&sh_p[brow][j0] = v;   // 8B-aligned (j0 even), all lanes distinct
  }
  __syncthreads();

  if (tid < NROWS * DOUT) {
    const int b = tid / DOUT;
    const int o = tid - b * DOUT;
    const float* fw = fc_W + o * H;
    float acc = fc_b[o];
#pragma unroll 4
    for (int k = 0; k < H; ++k) acc += sh_p[b][k] * fw[k];
    float sp = (acc > 15.f) ? acc : logf(1.f + expf(acc));
    out[(rb0 + b) * DOUT + o] = sp;
  }
}

extern "C" void kernel_launch(void* const* d_in, const int* in_sizes, int n_in,
                              void* d_out, int out_size, void* d_ws, size_t ws_size,
                              hipStream_t stream) {
  const float* x       = (const float*)d_in[0];
  const float* W_xh    = (const float*)d_in[1];
  const float* W_hh    = (const float*)d_in[2];
  const float* b_hh    = (const float*)d_in[3];
  const float* log_tau = (const float*)d_in[4];
  const float* fc_W    = (const float*)d_in[5];
  const float* fc_b    = (const float*)d_in[6];
  float* out           = (float*)d_out;

  ltc_kernel<<<dim3(B_TOT / NROWS), dim3(512), 0, stream>>>(
      x, W_xh, W_hh, b_hh, log_tau, fc_W, fc_b, out);
}